// Round 14
// baseline (257.130 us; speedup 1.0000x reference)
//
#include <hip/hip_runtime.h>

// R14: R13 with 1-WAVE workgroups (64 threads, grid E/16=8192). Wave-private
// pipeline has zero inter-wave coupling; 4-wave blocks were an artificial
// residency quantum (measured 21% occupancy vs 50% theoretical). LDS/block
// 8320B, launch_bounds(64,4) -> up to 16 waves/CU. Dataflow identical to R13.

typedef short  bf16x8 __attribute__((ext_vector_type(8)));
typedef float  f32x4  __attribute__((ext_vector_type(4)));

#define FENCE() asm volatile("" ::: "memory")

constexpr float BETA  = 1.6791767f;
constexpr float RS128 = 0.088388347648318447f;
constexpr float RS64  = 0.125f;
constexpr float RS32  = 0.176776695296636881f;
constexpr float RSQ3  = 0.577350269189625842f;

enum : int {
  O_nm1 = 0,      O_nm2 = 4096,   O_nm3 = 8192,
  O_em1 = 20480,  O_em2 = 24576,  O_em3 = 28672,
  O_nss = 40960,  O_nsv = 49152,  O_nvv = 53248,  O_nvs = 57344,
  O_ess = 59392,  O_esv = 63488,  O_evv = 65536,  O_evs = 67584,
  O_cns = 68608,  O_cnv = 76800,  O_ces = 78848,  O_cev = 87040,  // combined
  W_TOTAL = 89088
};

// arena column bases (per-wave [16][260] ushort)
enum : int { ST = 260, H0n = 0, H0e = 64, H1n = 128, H1e = 192, MSP = 0, MV = 128 };

struct Ptrs {
  const float *src, *dst, *ef, *env, *scal;
  const ushort* wf;
  float *out;
};

struct PrepArgs {
  const float* src[14];
  int K[14], N[14], ofs[14];
  ushort* dst;
};
struct Prep2Args {
  const float* A[4]; const float* B[4];
  int K[4], N[4], inner[4], ofs[4];
  float scale[4];
  ushort* dst;
};

__device__ __forceinline__ ushort f2b(float x) {
  union { float f; unsigned u; } v; v.f = x;
  unsigned r = v.u + 0x7fffu + ((v.u >> 16) & 1u);
  return (ushort)(r >> 16);
}
__device__ __forceinline__ unsigned pk2(float a, float b) {
  unsigned r;
  asm("v_cvt_pk_bf16_f32 %0, %1, %2" : "=v"(r) : "v"(a), "v"(b));
  return r;
}
__device__ __forceinline__ float plo(unsigned p) {
  union { unsigned u; float f; } v; v.u = p << 16; return v.f;
}
__device__ __forceinline__ float phi(unsigned p) {
  union { unsigned u; float f; } v; v.u = p & 0xffff0000u; return v.f;
}

__global__ __launch_bounds__(256) void prep_kernel(PrepArgs A) {
  const int mat = blockIdx.x;
  const float* __restrict__ src = A.src[mat];
  const int K = A.K[mat], N = A.N[mat], KS = K >> 5;
  ushort* dst = A.dst + A.ofs[mat];
  const int total = (N * K) >> 3;
  for (int gi = threadIdx.x; gi < total; gi += 256) {
    int t = gi / (64 * KS), r = gi - t * 64 * KS;
    int ks = r >> 6, lane = r & 63;
    int cc = lane & 15, gg = lane >> 4;
    int n = t * 16 + cc, k0 = ks * 32 + gg * 8;
    ushort v[8];
#pragma unroll
    for (int j = 0; j < 8; ++j) v[j] = f2b(src[(size_t)(k0 + j) * N + n]);
    *(uint4*)(dst + (size_t)gi * 8) = *(const uint4*)v;
  }
}

// combined W = (A @ B) * scale via LDS-staged operands, packed fragment-major.
__global__ __launch_bounds__(256) void prep2_kernel(Prep2Args Z) {
  const int m = blockIdx.x;
  const float* __restrict__ A = Z.A[m];
  const float* __restrict__ B = Z.B[m];
  const int K = Z.K[m], N = Z.N[m], I = Z.inner[m], KS = K >> 5;
  const float sc = Z.scale[m];
  ushort* dst = Z.dst + Z.ofs[m];

  __shared__ float sAt[8192];   // [I][K], max 64*128
  __shared__ float sB [4096];   // [I][N], max 64*64
  for (int idx = threadIdx.x; idx < K * I; idx += 256) {
    int k = idx / I, u = idx - k * I;
    sAt[u * K + k] = A[idx];
  }
  for (int idx = threadIdx.x; idx < I * N; idx += 256) sB[idx] = B[idx];
  __syncthreads();

  const int total = (N * K) >> 3;
  for (int gi = blockIdx.y * 256 + threadIdx.x; gi < total; gi += gridDim.y * 256) {
    int t = gi / (64 * KS), r = gi - t * 64 * KS;
    int ks = r >> 6, lane = r & 63;
    int cc = lane & 15, gg = lane >> 4;
    int n = t * 16 + cc, k0 = ks * 32 + gg * 8;
    float acc[8] = {0, 0, 0, 0, 0, 0, 0, 0};
    for (int u = 0; u < I; ++u) {
      float bv = sB[u * N + n];
      const float* ap = &sAt[u * K + k0];
#pragma unroll
      for (int j = 0; j < 8; ++j) acc[j] += ap[j] * bv;
    }
    ushort v[8];
#pragma unroll
    for (int j = 0; j < 8; ++j) v[j] = f2b(acc[j] * sc);
    *(uint4*)(dst + (size_t)gi * 8) = *(const uint4*)v;
  }
}

template<int N>
__device__ __forceinline__ void lda(const ushort* __restrict__ wb, unsigned lofs, bf16x8* a) {
#pragma unroll
  for (int i = 0; i < N; ++i) a[i] = *(const bf16x8*)(wb + i * 512 + lofs);
}
template<int T, int KS>
__device__ __forceinline__ void mfm(const bf16x8* a, const bf16x8* bf, f32x4* out) {
#pragma unroll
  for (int t = 0; t < T; ++t) {
    f32x4 acc = (f32x4){0, 0, 0, 0};
#pragma unroll
    for (int ks = 0; ks < KS; ++ks)
      acc = __builtin_amdgcn_mfma_f32_16x16x32_bf16(a[t * KS + ks], bf[ks], acc, 0, 0, 0);
    out[t] = acc;
  }
}
template<int T, int KS>
__device__ __forceinline__ void mfmacc(const bf16x8* a, const bf16x8* bf, f32x4* out) {
#pragma unroll
  for (int t = 0; t < T; ++t)
#pragma unroll
    for (int ks = 0; ks < KS; ++ks)
      out[t] = __builtin_amdgcn_mfma_f32_16x16x32_bf16(a[t * KS + ks], bf[ks], out[t], 0, 0, 0);
}

__device__ __forceinline__ void put2(ushort* b, int cg, int col, const f32x4& d) {
  uint2 p; p.x = pk2(d[0], d[1]); p.y = pk2(d[2], d[3]);
  *(uint2*)(b + cg + col) = p;
}
__device__ __forceinline__ bf16x8 getf(const ushort* b, int cg, int col, int g) {
  return *(const bf16x8*)(b + cg + col + 8 * g);
}
__device__ __forceinline__ bf16x8 ldf8(const float* __restrict__ p) {
  float4 a = *(const float4*)p, b4 = *(const float4*)(p + 4);
  union { unsigned u[4]; bf16x8 v; } r;
  r.u[0] = pk2(a.x, a.y); r.u[1] = pk2(a.z, a.w);
  r.u[2] = pk2(b4.x, b4.y); r.u[3] = pk2(b4.z, b4.w);
  return r.v;
}
__device__ __forceinline__ f32x4 silu4(const f32x4& d) {
  f32x4 o;
#pragma unroll
  for (int r = 0; r < 4; ++r) { float z = d[r] * 0.125f; o[r] = BETA * z / (1.f + __expf(-z)); }
  return o;
}
__device__ __forceinline__ void vecwin(const float* __restrict__ p,
                                       float y0, float y1, float y2,
                                       bf16x8& dotf, bf16x8* xvf) {
  float v[24];
#pragma unroll
  for (int q = 0; q < 6; ++q) *(float4*)&v[4 * q] = *(const float4*)(p + 4 * q);
  float dj[8];
#pragma unroll
  for (int j = 0; j < 8; ++j)
    dj[j] = (v[3 * j] * y0 + v[3 * j + 1] * y1 + v[3 * j + 2] * y2) * RSQ3;
  union { unsigned u[4]; bf16x8 w; } t;
#pragma unroll
  for (int q = 0; q < 4; ++q) t.u[q] = pk2(dj[2 * q], dj[2 * q + 1]);
  dotf = t.w;
#pragma unroll
  for (int i = 0; i < 3; ++i) {
#pragma unroll
    for (int q = 0; q < 4; ++q) t.u[q] = pk2(v[6 * q + i], v[6 * q + 3 + i]);
    xvf[i] = t.w;
  }
}

// MLP3 -> 12 packed w-tiles, chunked 3-tile rotation
__device__ __forceinline__ void mlp3(const ushort* __restrict__ wb, unsigned lofs,
                                     const bf16x8* h2, uint2* Wp) {
  bf16x8 aa[6], ab[6];
  lda<6>(wb, lofs, aa);
  lda<6>(wb + 6 * 512, lofs, ab);
  f32x4 dw[3];
  mfm<3, 2>(aa, h2, dw);
  lda<6>(wb + 12 * 512, lofs, aa);
#pragma unroll
  for (int t = 0; t < 3; ++t) { Wp[t].x = pk2(dw[t][0]*0.125f, dw[t][1]*0.125f); Wp[t].y = pk2(dw[t][2]*0.125f, dw[t][3]*0.125f); }
  mfm<3, 2>(ab, h2, dw);
  lda<6>(wb + 18 * 512, lofs, ab);
#pragma unroll
  for (int t = 0; t < 3; ++t) { Wp[3+t].x = pk2(dw[t][0]*0.125f, dw[t][1]*0.125f); Wp[3+t].y = pk2(dw[t][2]*0.125f, dw[t][3]*0.125f); }
  mfm<3, 2>(aa, h2, dw);
#pragma unroll
  for (int t = 0; t < 3; ++t) { Wp[6+t].x = pk2(dw[t][0]*0.125f, dw[t][1]*0.125f); Wp[6+t].y = pk2(dw[t][2]*0.125f, dw[t][3]*0.125f); }
  mfm<3, 2>(ab, h2, dw);
#pragma unroll
  for (int t = 0; t < 3; ++t) { Wp[9+t].x = pk2(dw[t][0]*0.125f, dw[t][1]*0.125f); Wp[9+t].y = pk2(dw[t][2]*0.125f, dw[t][3]*0.125f); }
}

// TP + folded SL for one path. ACC=false: overwrite os/ov; true: accumulate.
template<bool ED, bool ACC>
__device__ __forceinline__ void tp_sl(
    const ushort* __restrict__ WF, ushort* bA, int cg, int g, unsigned lofs,
    const bf16x8* xsf, const bf16x8* dotf, const bf16x8* xvi,
    const uint2* Wp, float ys, float yv0, float yv1, float yv2,
    f32x4* os, f32x4 (*ov)[2]) {
  constexpr int KA = ED ? 2 : 4;
  constexpr int KB = ED ? 1 : 2;
  const float SA = ED ? RS64 : RS128;
  const float SB = ED ? RS32 : RS64;

  // s_a -> MSP[0..63]
  {
    bf16x8 a[4 * KA]; f32x4 d[4];
    lda<4 * KA>(WF + (ED ? O_ess : O_nss), lofs, a);
    mfm<4, KA>(a, xsf, d);
#pragma unroll
    for (int t = 0; t < 4; ++t) {
      f32x4 m;
      m[0] = d[t][0]*ys*SA*plo(Wp[t].x); m[1] = d[t][1]*ys*SA*phi(Wp[t].x);
      m[2] = d[t][2]*ys*SA*plo(Wp[t].y); m[3] = d[t][3]*ys*SA*phi(Wp[t].y);
      put2(bA, cg, MSP + 16 * t + 4 * g, m);
    }
  }
  // s_b -> MSP[64..127]
  {
    bf16x8 a[4 * KB]; f32x4 d[4];
    lda<4 * KB>(WF + (ED ? O_evv : O_nvv), lofs, a);
    mfm<4, KB>(a, dotf, d);
#pragma unroll
    for (int t = 0; t < 4; ++t) {
      f32x4 m;
      m[0] = d[t][0]*SB*plo(Wp[4+t].x); m[1] = d[t][1]*SB*phi(Wp[4+t].x);
      m[2] = d[t][2]*SB*plo(Wp[4+t].y); m[3] = d[t][3]*SB*phi(Wp[4+t].y);
      put2(bA, cg, MSP + 64 + 16 * t + 4 * g, m);
    }
  }
  FENCE();
  // read mpf early; prefetch folded-SL weights
  bf16x8 mpf[4];
#pragma unroll
  for (int ks = 0; ks < 4; ++ks) mpf[ks] = getf(bA, cg, MSP + 32 * ks, g);
  bf16x8 acs[16];
  lda<16>(WF + (ED ? O_ces : O_cns), lofs, acs);

  // v_a shared tiles + per-i v_b -> MV scratch -> folded SL-v accumulate
  f32x4 ga[2];
  {
    bf16x8 a[2 * KA];
    lda<2 * KA>(WF + (ED ? O_esv : O_nsv), lofs, a);
    mfm<2, KA>(a, xsf, ga);
  }
  bf16x8 avs[2 * KB];
  lda<2 * KB>(WF + (ED ? O_evs : O_nvs), lofs, avs);
  bf16x8 acv[4];
  lda<4>(WF + (ED ? O_cev : O_cnv), lofs, acv);
#pragma unroll
  for (int i = 0; i < 3; ++i) {
    f32x4 db[2];
    mfm<2, KB>(avs, xvi + i * KB, db);
    float yvi = (i == 0) ? yv0 : ((i == 1) ? yv1 : yv2);
#pragma unroll
    for (int t = 0; t < 2; ++t) {
      f32x4 m;
      m[0] = ga[t][0]*SA*yvi*plo(Wp[8+t].x); m[1] = ga[t][1]*SA*yvi*phi(Wp[8+t].x);
      m[2] = ga[t][2]*SA*yvi*plo(Wp[8+t].y); m[3] = ga[t][3]*SA*yvi*phi(Wp[8+t].y);
      put2(bA, cg, MV + 16 * t + 4 * g, m);
    }
#pragma unroll
    for (int t = 0; t < 2; ++t) {
      f32x4 m;
      m[0] = db[t][0]*ys*SB*plo(Wp[10+t].x); m[1] = db[t][1]*ys*SB*phi(Wp[10+t].x);
      m[2] = db[t][2]*ys*SB*plo(Wp[10+t].y); m[3] = db[t][3]*ys*SB*phi(Wp[10+t].y);
      put2(bA, cg, MV + 32 + 16 * t + 4 * g, m);
    }
    FENCE();
    bf16x8 mvf[2] = { getf(bA, cg, MV, g), getf(bA, cg, MV + 32, g) };
    if (ACC) mfmacc<2, 2>(acv, mvf, ov[i]);
    else     mfm<2, 2>(acv, mvf, ov[i]);
    FENCE();   // ov read-back done before next i overwrites MV
  }
  // folded SL-s accumulate (mpf long since read)
  if (ACC) mfmacc<4, 4>(acs, mpf, os);
  else     mfm<4, 4>(acs, mpf, os);
}

__global__ __launch_bounds__(64, 4) void mp_kernel(Ptrs P) {
  const int lane = threadIdx.x & 63;
  const int c    = lane & 15, g  = lane >> 4;
  const unsigned lofs = lane * 8;
  const int cg   = c * ST;
  const int e    = blockIdx.x * 16 + c;
  const ushort* __restrict__ WF = P.wf;

  __shared__ ushort sb[16][ST];   // 8320 B per 1-wave block
  ushort* bA = &sb[0][0];

  const float* __restrict__ rs = P.src + (size_t)e * 160;
  const float* __restrict__ rd = P.dst + (size_t)e * 160;
  const float* __restrict__ re = P.ef  + (size_t)e * 160;
  const float* __restrict__ rq = P.scal + (size_t)e * 64;

  bf16x8 a1n[8], a1e[8];
  lda<8>(WF + O_nm1, lofs, a1n);
  lda<8>(WF + O_em1, lofs, a1e);

  float4 ev = *(const float4*)(P.env + (size_t)e * 4);
  const float ys = ev.x, yv0 = ev.y, yv1 = ev.z, yv2 = ev.w;
  bf16x8 sc[2];
  sc[0] = ldf8(rq + 8 * g);
  sc[1] = ldf8(rq + 32 + 8 * g);

  // ---- MLP1 (node+edge interleaved) ----
  {
    f32x4 dn[4], de[4];
    mfm<4, 2>(a1n, sc, dn); mfm<4, 2>(a1e, sc, de);
#pragma unroll
    for (int t = 0; t < 4; ++t) put2(bA, cg, H0n + 16 * t + 4 * g, silu4(dn[t]));
#pragma unroll
    for (int t = 0; t < 4; ++t) put2(bA, cg, H0e + 16 * t + 4 * g, silu4(de[t]));
  }
  FENCE();

  // ---- MLP2 + node TP input streams ----
  bf16x8 a2n[8], a2e[8];
  lda<8>(WF + O_nm2, lofs, a2n);
  lda<8>(WF + O_em2, lofs, a2e);
  bf16x8 xsf_n[4];
  xsf_n[0] = ldf8(rs + 8 * g);  xsf_n[1] = ldf8(rs + 32 + 8 * g);
  xsf_n[2] = ldf8(rd + 8 * g);  xsf_n[3] = ldf8(rd + 32 + 8 * g);
  bf16x8 dot_n[2], xv_n[6];
  {
    bf16x8 tmp[3];
    vecwin(rs + 64 + 24 * g, yv0, yv1, yv2, dot_n[0], tmp);
    xv_n[0] = tmp[0]; xv_n[2] = tmp[1]; xv_n[4] = tmp[2];
    vecwin(rd + 64 + 24 * g, yv0, yv1, yv2, dot_n[1], tmp);
    xv_n[1] = tmp[0]; xv_n[3] = tmp[1]; xv_n[5] = tmp[2];
  }
  {
    bf16x8 hn[2] = { getf(bA, cg, H0n, g), getf(bA, cg, H0n + 32, g) };
    bf16x8 he[2] = { getf(bA, cg, H0e, g), getf(bA, cg, H0e + 32, g) };
    f32x4 dn[4], de[4];
    mfm<4, 2>(a2n, hn, dn); mfm<4, 2>(a2e, he, de);
#pragma unroll
    for (int t = 0; t < 4; ++t) put2(bA, cg, H1n + 16 * t + 4 * g, silu4(dn[t]));
#pragma unroll
    for (int t = 0; t < 4; ++t) put2(bA, cg, H1e + 16 * t + 4 * g, silu4(de[t]));
  }
  FENCE();

  // ---- node MLP3 ----
  uint2 Wpn[12];
  {
    bf16x8 h2n[2] = { getf(bA, cg, H1n, g), getf(bA, cg, H1n + 32, g) };
    mlp3(WF + O_nm3, lofs, h2n, Wpn);
  }
  FENCE();   // H1n read complete before node TP overwrites MSP/MV

  // ---- node TP + folded SL (overwrite os/ov) ----
  f32x4 os[4]; f32x4 ov[3][2];
  tp_sl<false, false>(WF, bA, cg, g, lofs, xsf_n, dot_n, xv_n, Wpn, ys, yv0, yv1, yv2, os, ov);

  // ---- edge MLP3 (H1e still live at cols 192..255) + edge TP inputs ----
  bf16x8 xsf_e[2], dot_e[1], xv_e[3];
  xsf_e[0] = ldf8(re + 8 * g); xsf_e[1] = ldf8(re + 32 + 8 * g);
  {
    bf16x8 tmp[3];
    vecwin(re + 64 + 24 * g, yv0, yv1, yv2, dot_e[0], tmp);
    xv_e[0] = tmp[0]; xv_e[1] = tmp[1]; xv_e[2] = tmp[2];
  }
  uint2 Wpe[12];
  {
    bf16x8 h2e[2] = { getf(bA, cg, H1e, g), getf(bA, cg, H1e + 32, g) };
    mlp3(WF + O_em3, lofs, h2e, Wpe);
  }
  FENCE();

  // ---- edge TP + folded SL (accumulate) ----
  tp_sl<true, true>(WF, bA, cg, g, lofs, xsf_e, dot_e, xv_e, Wpe, ys, yv0, yv1, yv2, os, ov);

  // ---- store (scales baked into combined weights) ----
  float* __restrict__ po = P.out + (size_t)e * 160;
#pragma unroll
  for (int t = 0; t < 4; ++t) {
    float4 o = { os[t][0], os[t][1], os[t][2], os[t][3] };
    *(float4*)(po + 16 * t + 4 * g) = o;
  }
#pragma unroll
  for (int t = 0; t < 2; ++t) {
    float vv[12];
#pragma unroll
    for (int r = 0; r < 4; ++r)
#pragma unroll
      for (int i = 0; i < 3; ++i) vv[3 * r + i] = ov[i][t][r];
    *(float4*)(po + 64 + 48 * t + 12 * g)     = *(float4*)&vv[0];
    *(float4*)(po + 64 + 48 * t + 12 * g + 4) = *(float4*)&vv[4];
    *(float4*)(po + 64 + 48 * t + 12 * g + 8) = *(float4*)&vv[8];
  }
}

extern "C" void kernel_launch(void* const* d_in, const int* in_sizes, int n_in,
                              void* d_out, int out_size, void* d_ws, size_t ws_size,
                              hipStream_t stream) {
  PrepArgs A;
  const int src_idx[14] = {21,22,23, 24,25,26, 5,7,6,8, 9,11,10,12};
  const int Ks[14] = {64,64,64, 64,64,64, 128,128,64,64, 64,64,32,32};
  const int Ns[14] = {64,64,192, 64,64,192, 64,32,64,32, 64,32,64,32};
  const int Os[14] = {O_nm1,O_nm2,O_nm3, O_em1,O_em2,O_em3,
                      O_nss,O_nsv,O_nvv,O_nvs, O_ess,O_esv,O_evv,O_evs};
  for (int i = 0; i < 14; ++i) {
    A.src[i] = (const float*)d_in[src_idx[i]];
    A.K[i] = Ks[i]; A.N[i] = Ns[i]; A.ofs[i] = Os[i];
  }
  A.dst = (ushort*)d_ws;
  prep_kernel<<<dim3(14), dim3(256), 0, stream>>>(A);

  Prep2Args Z;
  Z.A[0] = (const float*)d_in[13]; Z.B[0] = (const float*)d_in[17];
  Z.K[0] = 128; Z.N[0] = 64; Z.inner[0] = 64; Z.ofs[0] = O_cns; Z.scale[0] = RS128 * RS64;
  Z.A[1] = (const float*)d_in[14]; Z.B[1] = (const float*)d_in[18];
  Z.K[1] = 64;  Z.N[1] = 32; Z.inner[1] = 32; Z.ofs[1] = O_cnv; Z.scale[1] = RS64 * RS32;
  Z.A[2] = (const float*)d_in[15]; Z.B[2] = (const float*)d_in[19];
  Z.K[2] = 128; Z.N[2] = 64; Z.inner[2] = 64; Z.ofs[2] = O_ces; Z.scale[2] = RS128 * RS64;
  Z.A[3] = (const float*)d_in[16]; Z.B[3] = (const float*)d_in[20];
  Z.K[3] = 64;  Z.N[3] = 32; Z.inner[3] = 32; Z.ofs[3] = O_cev; Z.scale[3] = RS64 * RS32;
  Z.dst = (ushort*)d_ws;
  prep2_kernel<<<dim3(4, 4), dim3(256), 0, stream>>>(Z);

  Ptrs P;
  P.src  = (const float*)d_in[0];
  P.dst  = (const float*)d_in[1];
  P.ef   = (const float*)d_in[2];
  P.env  = (const float*)d_in[3];
  P.scal = (const float*)d_in[4];
  P.wf   = (const ushort*)d_ws;
  P.out  = (float*)d_out;

  const int E = in_sizes[0] / 160;  // 131072
  mp_kernel<<<dim3(E / 16), dim3(64), 0, stream>>>(P);
}

// Round 15
// 148.560 us; speedup vs baseline: 1.7308x; 1.7308x over previous
//
#include <hip/hip_runtime.h>

// R15: R14 (1-wave workgroups, grid E/16) with the register cap removed:
// __launch_bounds__(64,2) -> VGPR cap 256; structure allocates ~124 (R13) so
// HW still fits 4 waves/SIMD and 16 blocks x 8.7KB = 139KB LDS/CU. Keeps
// R14's residency gain (occupancy 21->41%) without R14's spill (VGPR=64,
// 395MB scratch writes). Dataflow identical to R13/R14.

typedef short  bf16x8 __attribute__((ext_vector_type(8)));
typedef float  f32x4  __attribute__((ext_vector_type(4)));

#define FENCE() asm volatile("" ::: "memory")

constexpr float BETA  = 1.6791767f;
constexpr float RS128 = 0.088388347648318447f;
constexpr float RS64  = 0.125f;
constexpr float RS32  = 0.176776695296636881f;
constexpr float RSQ3  = 0.577350269189625842f;

enum : int {
  O_nm1 = 0,      O_nm2 = 4096,   O_nm3 = 8192,
  O_em1 = 20480,  O_em2 = 24576,  O_em3 = 28672,
  O_nss = 40960,  O_nsv = 49152,  O_nvv = 53248,  O_nvs = 57344,
  O_ess = 59392,  O_esv = 63488,  O_evv = 65536,  O_evs = 67584,
  O_cns = 68608,  O_cnv = 76800,  O_ces = 78848,  O_cev = 87040,  // combined
  W_TOTAL = 89088
};

// arena column bases (per-wave [16][260] ushort)
enum : int { ST = 260, H0n = 0, H0e = 64, H1n = 128, H1e = 192, MSP = 0, MV = 128 };

struct Ptrs {
  const float *src, *dst, *ef, *env, *scal;
  const ushort* wf;
  float *out;
};

struct PrepArgs {
  const float* src[14];
  int K[14], N[14], ofs[14];
  ushort* dst;
};
struct Prep2Args {
  const float* A[4]; const float* B[4];
  int K[4], N[4], inner[4], ofs[4];
  float scale[4];
  ushort* dst;
};

__device__ __forceinline__ ushort f2b(float x) {
  union { float f; unsigned u; } v; v.f = x;
  unsigned r = v.u + 0x7fffu + ((v.u >> 16) & 1u);
  return (ushort)(r >> 16);
}
__device__ __forceinline__ unsigned pk2(float a, float b) {
  unsigned r;
  asm("v_cvt_pk_bf16_f32 %0, %1, %2" : "=v"(r) : "v"(a), "v"(b));
  return r;
}
__device__ __forceinline__ float plo(unsigned p) {
  union { unsigned u; float f; } v; v.u = p << 16; return v.f;
}
__device__ __forceinline__ float phi(unsigned p) {
  union { unsigned u; float f; } v; v.u = p & 0xffff0000u; return v.f;
}

__global__ __launch_bounds__(256) void prep_kernel(PrepArgs A) {
  const int mat = blockIdx.x;
  const float* __restrict__ src = A.src[mat];
  const int K = A.K[mat], N = A.N[mat], KS = K >> 5;
  ushort* dst = A.dst + A.ofs[mat];
  const int total = (N * K) >> 3;
  for (int gi = threadIdx.x; gi < total; gi += 256) {
    int t = gi / (64 * KS), r = gi - t * 64 * KS;
    int ks = r >> 6, lane = r & 63;
    int cc = lane & 15, gg = lane >> 4;
    int n = t * 16 + cc, k0 = ks * 32 + gg * 8;
    ushort v[8];
#pragma unroll
    for (int j = 0; j < 8; ++j) v[j] = f2b(src[(size_t)(k0 + j) * N + n]);
    *(uint4*)(dst + (size_t)gi * 8) = *(const uint4*)v;
  }
}

// combined W = (A @ B) * scale via LDS-staged operands, packed fragment-major.
__global__ __launch_bounds__(256) void prep2_kernel(Prep2Args Z) {
  const int m = blockIdx.x;
  const float* __restrict__ A = Z.A[m];
  const float* __restrict__ B = Z.B[m];
  const int K = Z.K[m], N = Z.N[m], I = Z.inner[m], KS = K >> 5;
  const float sc = Z.scale[m];
  ushort* dst = Z.dst + Z.ofs[m];

  __shared__ float sAt[8192];   // [I][K], max 64*128
  __shared__ float sB [4096];   // [I][N], max 64*64
  for (int idx = threadIdx.x; idx < K * I; idx += 256) {
    int k = idx / I, u = idx - k * I;
    sAt[u * K + k] = A[idx];
  }
  for (int idx = threadIdx.x; idx < I * N; idx += 256) sB[idx] = B[idx];
  __syncthreads();

  const int total = (N * K) >> 3;
  for (int gi = blockIdx.y * 256 + threadIdx.x; gi < total; gi += gridDim.y * 256) {
    int t = gi / (64 * KS), r = gi - t * 64 * KS;
    int ks = r >> 6, lane = r & 63;
    int cc = lane & 15, gg = lane >> 4;
    int n = t * 16 + cc, k0 = ks * 32 + gg * 8;
    float acc[8] = {0, 0, 0, 0, 0, 0, 0, 0};
    for (int u = 0; u < I; ++u) {
      float bv = sB[u * N + n];
      const float* ap = &sAt[u * K + k0];
#pragma unroll
      for (int j = 0; j < 8; ++j) acc[j] += ap[j] * bv;
    }
    ushort v[8];
#pragma unroll
    for (int j = 0; j < 8; ++j) v[j] = f2b(acc[j] * sc);
    *(uint4*)(dst + (size_t)gi * 8) = *(const uint4*)v;
  }
}

template<int N>
__device__ __forceinline__ void lda(const ushort* __restrict__ wb, unsigned lofs, bf16x8* a) {
#pragma unroll
  for (int i = 0; i < N; ++i) a[i] = *(const bf16x8*)(wb + i * 512 + lofs);
}
template<int T, int KS>
__device__ __forceinline__ void mfm(const bf16x8* a, const bf16x8* bf, f32x4* out) {
#pragma unroll
  for (int t = 0; t < T; ++t) {
    f32x4 acc = (f32x4){0, 0, 0, 0};
#pragma unroll
    for (int ks = 0; ks < KS; ++ks)
      acc = __builtin_amdgcn_mfma_f32_16x16x32_bf16(a[t * KS + ks], bf[ks], acc, 0, 0, 0);
    out[t] = acc;
  }
}
template<int T, int KS>
__device__ __forceinline__ void mfmacc(const bf16x8* a, const bf16x8* bf, f32x4* out) {
#pragma unroll
  for (int t = 0; t < T; ++t)
#pragma unroll
    for (int ks = 0; ks < KS; ++ks)
      out[t] = __builtin_amdgcn_mfma_f32_16x16x32_bf16(a[t * KS + ks], bf[ks], out[t], 0, 0, 0);
}

__device__ __forceinline__ void put2(ushort* b, int cg, int col, const f32x4& d) {
  uint2 p; p.x = pk2(d[0], d[1]); p.y = pk2(d[2], d[3]);
  *(uint2*)(b + cg + col) = p;
}
__device__ __forceinline__ bf16x8 getf(const ushort* b, int cg, int col, int g) {
  return *(const bf16x8*)(b + cg + col + 8 * g);
}
__device__ __forceinline__ bf16x8 ldf8(const float* __restrict__ p) {
  float4 a = *(const float4*)p, b4 = *(const float4*)(p + 4);
  union { unsigned u[4]; bf16x8 v; } r;
  r.u[0] = pk2(a.x, a.y); r.u[1] = pk2(a.z, a.w);
  r.u[2] = pk2(b4.x, b4.y); r.u[3] = pk2(b4.z, b4.w);
  return r.v;
}
__device__ __forceinline__ f32x4 silu4(const f32x4& d) {
  f32x4 o;
#pragma unroll
  for (int r = 0; r < 4; ++r) { float z = d[r] * 0.125f; o[r] = BETA * z / (1.f + __expf(-z)); }
  return o;
}
__device__ __forceinline__ void vecwin(const float* __restrict__ p,
                                       float y0, float y1, float y2,
                                       bf16x8& dotf, bf16x8* xvf) {
  float v[24];
#pragma unroll
  for (int q = 0; q < 6; ++q) *(float4*)&v[4 * q] = *(const float4*)(p + 4 * q);
  float dj[8];
#pragma unroll
  for (int j = 0; j < 8; ++j)
    dj[j] = (v[3 * j] * y0 + v[3 * j + 1] * y1 + v[3 * j + 2] * y2) * RSQ3;
  union { unsigned u[4]; bf16x8 w; } t;
#pragma unroll
  for (int q = 0; q < 4; ++q) t.u[q] = pk2(dj[2 * q], dj[2 * q + 1]);
  dotf = t.w;
#pragma unroll
  for (int i = 0; i < 3; ++i) {
#pragma unroll
    for (int q = 0; q < 4; ++q) t.u[q] = pk2(v[6 * q + i], v[6 * q + 3 + i]);
    xvf[i] = t.w;
  }
}

// MLP3 -> 12 packed w-tiles, chunked 3-tile rotation
__device__ __forceinline__ void mlp3(const ushort* __restrict__ wb, unsigned lofs,
                                     const bf16x8* h2, uint2* Wp) {
  bf16x8 aa[6], ab[6];
  lda<6>(wb, lofs, aa);
  lda<6>(wb + 6 * 512, lofs, ab);
  f32x4 dw[3];
  mfm<3, 2>(aa, h2, dw);
  lda<6>(wb + 12 * 512, lofs, aa);
#pragma unroll
  for (int t = 0; t < 3; ++t) { Wp[t].x = pk2(dw[t][0]*0.125f, dw[t][1]*0.125f); Wp[t].y = pk2(dw[t][2]*0.125f, dw[t][3]*0.125f); }
  mfm<3, 2>(ab, h2, dw);
  lda<6>(wb + 18 * 512, lofs, ab);
#pragma unroll
  for (int t = 0; t < 3; ++t) { Wp[3+t].x = pk2(dw[t][0]*0.125f, dw[t][1]*0.125f); Wp[3+t].y = pk2(dw[t][2]*0.125f, dw[t][3]*0.125f); }
  mfm<3, 2>(aa, h2, dw);
#pragma unroll
  for (int t = 0; t < 3; ++t) { Wp[6+t].x = pk2(dw[t][0]*0.125f, dw[t][1]*0.125f); Wp[6+t].y = pk2(dw[t][2]*0.125f, dw[t][3]*0.125f); }
  mfm<3, 2>(ab, h2, dw);
#pragma unroll
  for (int t = 0; t < 3; ++t) { Wp[9+t].x = pk2(dw[t][0]*0.125f, dw[t][1]*0.125f); Wp[9+t].y = pk2(dw[t][2]*0.125f, dw[t][3]*0.125f); }
}

// TP + folded SL for one path. ACC=false: overwrite os/ov; true: accumulate.
template<bool ED, bool ACC>
__device__ __forceinline__ void tp_sl(
    const ushort* __restrict__ WF, ushort* bA, int cg, int g, unsigned lofs,
    const bf16x8* xsf, const bf16x8* dotf, const bf16x8* xvi,
    const uint2* Wp, float ys, float yv0, float yv1, float yv2,
    f32x4* os, f32x4 (*ov)[2]) {
  constexpr int KA = ED ? 2 : 4;
  constexpr int KB = ED ? 1 : 2;
  const float SA = ED ? RS64 : RS128;
  const float SB = ED ? RS32 : RS64;

  // s_a -> MSP[0..63]
  {
    bf16x8 a[4 * KA]; f32x4 d[4];
    lda<4 * KA>(WF + (ED ? O_ess : O_nss), lofs, a);
    mfm<4, KA>(a, xsf, d);
#pragma unroll
    for (int t = 0; t < 4; ++t) {
      f32x4 m;
      m[0] = d[t][0]*ys*SA*plo(Wp[t].x); m[1] = d[t][1]*ys*SA*phi(Wp[t].x);
      m[2] = d[t][2]*ys*SA*plo(Wp[t].y); m[3] = d[t][3]*ys*SA*phi(Wp[t].y);
      put2(bA, cg, MSP + 16 * t + 4 * g, m);
    }
  }
  // s_b -> MSP[64..127]
  {
    bf16x8 a[4 * KB]; f32x4 d[4];
    lda<4 * KB>(WF + (ED ? O_evv : O_nvv), lofs, a);
    mfm<4, KB>(a, dotf, d);
#pragma unroll
    for (int t = 0; t < 4; ++t) {
      f32x4 m;
      m[0] = d[t][0]*SB*plo(Wp[4+t].x); m[1] = d[t][1]*SB*phi(Wp[4+t].x);
      m[2] = d[t][2]*SB*plo(Wp[4+t].y); m[3] = d[t][3]*SB*phi(Wp[4+t].y);
      put2(bA, cg, MSP + 64 + 16 * t + 4 * g, m);
    }
  }
  FENCE();
  // read mpf early; prefetch folded-SL weights
  bf16x8 mpf[4];
#pragma unroll
  for (int ks = 0; ks < 4; ++ks) mpf[ks] = getf(bA, cg, MSP + 32 * ks, g);
  bf16x8 acs[16];
  lda<16>(WF + (ED ? O_ces : O_cns), lofs, acs);

  // v_a shared tiles + per-i v_b -> MV scratch -> folded SL-v accumulate
  f32x4 ga[2];
  {
    bf16x8 a[2 * KA];
    lda<2 * KA>(WF + (ED ? O_esv : O_nsv), lofs, a);
    mfm<2, KA>(a, xsf, ga);
  }
  bf16x8 avs[2 * KB];
  lda<2 * KB>(WF + (ED ? O_evs : O_nvs), lofs, avs);
  bf16x8 acv[4];
  lda<4>(WF + (ED ? O_cev : O_cnv), lofs, acv);
#pragma unroll
  for (int i = 0; i < 3; ++i) {
    f32x4 db[2];
    mfm<2, KB>(avs, xvi + i * KB, db);
    float yvi = (i == 0) ? yv0 : ((i == 1) ? yv1 : yv2);
#pragma unroll
    for (int t = 0; t < 2; ++t) {
      f32x4 m;
      m[0] = ga[t][0]*SA*yvi*plo(Wp[8+t].x); m[1] = ga[t][1]*SA*yvi*phi(Wp[8+t].x);
      m[2] = ga[t][2]*SA*yvi*plo(Wp[8+t].y); m[3] = ga[t][3]*SA*yvi*phi(Wp[8+t].y);
      put2(bA, cg, MV + 16 * t + 4 * g, m);
    }
#pragma unroll
    for (int t = 0; t < 2; ++t) {
      f32x4 m;
      m[0] = db[t][0]*ys*SB*plo(Wp[10+t].x); m[1] = db[t][1]*ys*SB*phi(Wp[10+t].x);
      m[2] = db[t][2]*ys*SB*plo(Wp[10+t].y); m[3] = db[t][3]*ys*SB*phi(Wp[10+t].y);
      put2(bA, cg, MV + 32 + 16 * t + 4 * g, m);
    }
    FENCE();
    bf16x8 mvf[2] = { getf(bA, cg, MV, g), getf(bA, cg, MV + 32, g) };
    if (ACC) mfmacc<2, 2>(acv, mvf, ov[i]);
    else     mfm<2, 2>(acv, mvf, ov[i]);
    FENCE();   // ov read-back done before next i overwrites MV
  }
  // folded SL-s accumulate (mpf long since read)
  if (ACC) mfmacc<4, 4>(acs, mpf, os);
  else     mfm<4, 4>(acs, mpf, os);
}

__global__ __launch_bounds__(64, 2) void mp_kernel(Ptrs P) {
  const int lane = threadIdx.x & 63;
  const int c    = lane & 15, g  = lane >> 4;
  const unsigned lofs = lane * 8;
  const int cg   = c * ST;
  const int e    = blockIdx.x * 16 + c;
  const ushort* __restrict__ WF = P.wf;

  __shared__ ushort sb[16][ST];   // 8320 B per 1-wave block
  ushort* bA = &sb[0][0];

  const float* __restrict__ rs = P.src + (size_t)e * 160;
  const float* __restrict__ rd = P.dst + (size_t)e * 160;
  const float* __restrict__ re = P.ef  + (size_t)e * 160;
  const float* __restrict__ rq = P.scal + (size_t)e * 64;

  bf16x8 a1n[8], a1e[8];
  lda<8>(WF + O_nm1, lofs, a1n);
  lda<8>(WF + O_em1, lofs, a1e);

  float4 ev = *(const float4*)(P.env + (size_t)e * 4);
  const float ys = ev.x, yv0 = ev.y, yv1 = ev.z, yv2 = ev.w;
  bf16x8 sc[2];
  sc[0] = ldf8(rq + 8 * g);
  sc[1] = ldf8(rq + 32 + 8 * g);

  // ---- MLP1 (node+edge interleaved) ----
  {
    f32x4 dn[4], de[4];
    mfm<4, 2>(a1n, sc, dn); mfm<4, 2>(a1e, sc, de);
#pragma unroll
    for (int t = 0; t < 4; ++t) put2(bA, cg, H0n + 16 * t + 4 * g, silu4(dn[t]));
#pragma unroll
    for (int t = 0; t < 4; ++t) put2(bA, cg, H0e + 16 * t + 4 * g, silu4(de[t]));
  }
  FENCE();

  // ---- MLP2 + node TP input streams ----
  bf16x8 a2n[8], a2e[8];
  lda<8>(WF + O_nm2, lofs, a2n);
  lda<8>(WF + O_em2, lofs, a2e);
  bf16x8 xsf_n[4];
  xsf_n[0] = ldf8(rs + 8 * g);  xsf_n[1] = ldf8(rs + 32 + 8 * g);
  xsf_n[2] = ldf8(rd + 8 * g);  xsf_n[3] = ldf8(rd + 32 + 8 * g);
  bf16x8 dot_n[2], xv_n[6];
  {
    bf16x8 tmp[3];
    vecwin(rs + 64 + 24 * g, yv0, yv1, yv2, dot_n[0], tmp);
    xv_n[0] = tmp[0]; xv_n[2] = tmp[1]; xv_n[4] = tmp[2];
    vecwin(rd + 64 + 24 * g, yv0, yv1, yv2, dot_n[1], tmp);
    xv_n[1] = tmp[0]; xv_n[3] = tmp[1]; xv_n[5] = tmp[2];
  }
  {
    bf16x8 hn[2] = { getf(bA, cg, H0n, g), getf(bA, cg, H0n + 32, g) };
    bf16x8 he[2] = { getf(bA, cg, H0e, g), getf(bA, cg, H0e + 32, g) };
    f32x4 dn[4], de[4];
    mfm<4, 2>(a2n, hn, dn); mfm<4, 2>(a2e, he, de);
#pragma unroll
    for (int t = 0; t < 4; ++t) put2(bA, cg, H1n + 16 * t + 4 * g, silu4(dn[t]));
#pragma unroll
    for (int t = 0; t < 4; ++t) put2(bA, cg, H1e + 16 * t + 4 * g, silu4(de[t]));
  }
  FENCE();

  // ---- node MLP3 ----
  uint2 Wpn[12];
  {
    bf16x8 h2n[2] = { getf(bA, cg, H1n, g), getf(bA, cg, H1n + 32, g) };
    mlp3(WF + O_nm3, lofs, h2n, Wpn);
  }
  FENCE();   // H1n read complete before node TP overwrites MSP/MV

  // ---- node TP + folded SL (overwrite os/ov) ----
  f32x4 os[4]; f32x4 ov[3][2];
  tp_sl<false, false>(WF, bA, cg, g, lofs, xsf_n, dot_n, xv_n, Wpn, ys, yv0, yv1, yv2, os, ov);

  // ---- edge MLP3 (H1e still live at cols 192..255) + edge TP inputs ----
  bf16x8 xsf_e[2], dot_e[1], xv_e[3];
  xsf_e[0] = ldf8(re + 8 * g); xsf_e[1] = ldf8(re + 32 + 8 * g);
  {
    bf16x8 tmp[3];
    vecwin(re + 64 + 24 * g, yv0, yv1, yv2, dot_e[0], tmp);
    xv_e[0] = tmp[0]; xv_e[1] = tmp[1]; xv_e[2] = tmp[2];
  }
  uint2 Wpe[12];
  {
    bf16x8 h2e[2] = { getf(bA, cg, H1e, g), getf(bA, cg, H1e + 32, g) };
    mlp3(WF + O_em3, lofs, h2e, Wpe);
  }
  FENCE();

  // ---- edge TP + folded SL (accumulate) ----
  tp_sl<true, true>(WF, bA, cg, g, lofs, xsf_e, dot_e, xv_e, Wpe, ys, yv0, yv1, yv2, os, ov);

  // ---- store (scales baked into combined weights) ----
  float* __restrict__ po = P.out + (size_t)e * 160;
#pragma unroll
  for (int t = 0; t < 4; ++t) {
    float4 o = { os[t][0], os[t][1], os[t][2], os[t][3] };
    *(float4*)(po + 16 * t + 4 * g) = o;
  }
#pragma unroll
  for (int t = 0; t < 2; ++t) {
    float vv[12];
#pragma unroll
    for (int r = 0; r < 4; ++r)
#pragma unroll
      for (int i = 0; i < 3; ++i) vv[3 * r + i] = ov[i][t][r];
    *(float4*)(po + 64 + 48 * t + 12 * g)     = *(float4*)&vv[0];
    *(float4*)(po + 64 + 48 * t + 12 * g + 4) = *(float4*)&vv[4];
    *(float4*)(po + 64 + 48 * t + 12 * g + 8) = *(float4*)&vv[8];
  }
}

extern "C" void kernel_launch(void* const* d_in, const int* in_sizes, int n_in,
                              void* d_out, int out_size, void* d_ws, size_t ws_size,
                              hipStream_t stream) {
  PrepArgs A;
  const int src_idx[14] = {21,22,23, 24,25,26, 5,7,6,8, 9,11,10,12};
  const int Ks[14] = {64,64,64, 64,64,64, 128,128,64,64, 64,64,32,32};
  const int Ns[14] = {64,64,192, 64,64,192, 64,32,64,32, 64,32,64,32};
  const int Os[14] = {O_nm1,O_nm2,O_nm3, O_em1,O_em2,O_em3,
                      O_nss,O_nsv,O_nvv,O_nvs, O_ess,O_esv,O_evv,O_evs};
  for (int i = 0; i < 14; ++i) {
    A.src[i] = (const float*)d_in[src_idx[i]];
    A.K[i] = Ks[i]; A.N[i] = Ns[i]; A.ofs[i] = Os[i];
  }
  A.dst = (ushort*)d_ws;
  prep_kernel<<<dim3(14), dim3(256), 0, stream>>>(A);

  Prep2Args Z;
  Z.A[0] = (const float*)d_in[13]; Z.B[0] = (const float*)d_in[17];
  Z.K[0] = 128; Z.N[0] = 64; Z.inner[0] = 64; Z.ofs[0] = O_cns; Z.scale[0] = RS128 * RS64;
  Z.A[1] = (const float*)d_in[14]; Z.B[1] = (const float*)d_in[18];
  Z.K[1] = 64;  Z.N[1] = 32; Z.inner[1] = 32; Z.ofs[1] = O_cnv; Z.scale[1] = RS64 * RS32;
  Z.A[2] = (const float*)d_in[15]; Z.B[2] = (const float*)d_in[19];
  Z.K[2] = 128; Z.N[2] = 64; Z.inner[2] = 64; Z.ofs[2] = O_ces; Z.scale[2] = RS128 * RS64;
  Z.A[3] = (const float*)d_in[16]; Z.B[3] = (const float*)d_in[20];
  Z.K[3] = 64;  Z.N[3] = 32; Z.inner[3] = 32; Z.ofs[3] = O_cev; Z.scale[3] = RS64 * RS32;
  Z.dst = (ushort*)d_ws;
  prep2_kernel<<<dim3(4, 4), dim3(256), 0, stream>>>(Z);

  Ptrs P;
  P.src  = (const float*)d_in[0];
  P.dst  = (const float*)d_in[1];
  P.ef   = (const float*)d_in[2];
  P.env  = (const float*)d_in[3];
  P.scal = (const float*)d_in[4];
  P.wf   = (const ushort*)d_ws;
  P.out  = (float*)d_out;

  const int E = in_sizes[0] / 160;  // 131072
  mp_kernel<<<dim3(E / 16), dim3(64), 0, stream>>>(P);
}

// Round 16
// 138.946 us; speedup vs baseline: 1.8506x; 1.0692x over previous
//
#include <hip/hip_runtime.h>

// R16: 32 edges/wave (two 16-edge groups A/B) sharing ALL weight-fragment
// loads -> weight bytes + load-issue per edge halved. 1-wave WGs, grid E/32.
// Verified 16x16x32 fragment layouts unchanged. Weight batches chunked <=8
// frags; MLP3 4x6-frag sequential chunks; reg peak target ~230 (cap 256).

typedef short  bf16x8 __attribute__((ext_vector_type(8)));
typedef float  f32x4  __attribute__((ext_vector_type(4)));

#define FENCE() asm volatile("" ::: "memory")

constexpr float BETA  = 1.6791767f;
constexpr float RS128 = 0.088388347648318447f;
constexpr float RS64  = 0.125f;
constexpr float RS32  = 0.176776695296636881f;
constexpr float RSQ3  = 0.577350269189625842f;

enum : int {
  O_nm1 = 0,      O_nm2 = 4096,   O_nm3 = 8192,
  O_em1 = 20480,  O_em2 = 24576,  O_em3 = 28672,
  O_nss = 40960,  O_nsv = 49152,  O_nvv = 53248,  O_nvs = 57344,
  O_ess = 59392,  O_esv = 63488,  O_evv = 65536,  O_evs = 67584,
  O_cns = 68608,  O_cnv = 76800,  O_ces = 78848,  O_cev = 87040,
  W_TOTAL = 89088
};

enum : int { ST = 260, H0n = 0, H0e = 64, H1n = 128, H1e = 192, MSP = 0, MV = 128 };

struct Ptrs {
  const float *src, *dst, *ef, *env, *scal;
  const ushort* wf;
  float *out;
};

struct PrepArgs {
  const float* src[14];
  int K[14], N[14], ofs[14];
  ushort* dst;
};
struct Prep2Args {
  const float* A[4]; const float* B[4];
  int K[4], N[4], inner[4], ofs[4];
  float scale[4];
  ushort* dst;
};

__device__ __forceinline__ ushort f2b(float x) {
  union { float f; unsigned u; } v; v.f = x;
  unsigned r = v.u + 0x7fffu + ((v.u >> 16) & 1u);
  return (ushort)(r >> 16);
}
__device__ __forceinline__ unsigned pk2(float a, float b) {
  unsigned r;
  asm("v_cvt_pk_bf16_f32 %0, %1, %2" : "=v"(r) : "v"(a), "v"(b));
  return r;
}
__device__ __forceinline__ float plo(unsigned p) {
  union { unsigned u; float f; } v; v.u = p << 16; return v.f;
}
__device__ __forceinline__ float phi(unsigned p) {
  union { unsigned u; float f; } v; v.u = p & 0xffff0000u; return v.f;
}

__global__ __launch_bounds__(256) void prep_kernel(PrepArgs A) {
  const int mat = blockIdx.x;
  const float* __restrict__ src = A.src[mat];
  const int K = A.K[mat], N = A.N[mat], KS = K >> 5;
  ushort* dst = A.dst + A.ofs[mat];
  const int total = (N * K) >> 3;
  for (int gi = threadIdx.x; gi < total; gi += 256) {
    int t = gi / (64 * KS), r = gi - t * 64 * KS;
    int ks = r >> 6, lane = r & 63;
    int cc = lane & 15, gg = lane >> 4;
    int n = t * 16 + cc, k0 = ks * 32 + gg * 8;
    ushort v[8];
#pragma unroll
    for (int j = 0; j < 8; ++j) v[j] = f2b(src[(size_t)(k0 + j) * N + n]);
    *(uint4*)(dst + (size_t)gi * 8) = *(const uint4*)v;
  }
}

__global__ __launch_bounds__(256) void prep2_kernel(Prep2Args Z) {
  const int m = blockIdx.x;
  const float* __restrict__ A = Z.A[m];
  const float* __restrict__ B = Z.B[m];
  const int K = Z.K[m], N = Z.N[m], I = Z.inner[m], KS = K >> 5;
  const float sc = Z.scale[m];
  ushort* dst = Z.dst + Z.ofs[m];

  __shared__ float sAt[8192];
  __shared__ float sB [4096];
  for (int idx = threadIdx.x; idx < K * I; idx += 256) {
    int k = idx / I, u = idx - k * I;
    sAt[u * K + k] = A[idx];
  }
  for (int idx = threadIdx.x; idx < I * N; idx += 256) sB[idx] = B[idx];
  __syncthreads();

  const int total = (N * K) >> 3;
  for (int gi = blockIdx.y * 256 + threadIdx.x; gi < total; gi += gridDim.y * 256) {
    int t = gi / (64 * KS), r = gi - t * 64 * KS;
    int ks = r >> 6, lane = r & 63;
    int cc = lane & 15, gg = lane >> 4;
    int n = t * 16 + cc, k0 = ks * 32 + gg * 8;
    float acc[8] = {0, 0, 0, 0, 0, 0, 0, 0};
    for (int u = 0; u < I; ++u) {
      float bv = sB[u * N + n];
      const float* ap = &sAt[u * K + k0];
#pragma unroll
      for (int j = 0; j < 8; ++j) acc[j] += ap[j] * bv;
    }
    ushort v[8];
#pragma unroll
    for (int j = 0; j < 8; ++j) v[j] = f2b(acc[j] * sc);
    *(uint4*)(dst + (size_t)gi * 8) = *(const uint4*)v;
  }
}

template<int N>
__device__ __forceinline__ void lda(const ushort* __restrict__ wb, unsigned lofs, bf16x8* a) {
#pragma unroll
  for (int i = 0; i < N; ++i) a[i] = *(const bf16x8*)(wb + i * 512 + lofs);
}
template<int T, int KS>
__device__ __forceinline__ void mfm(const bf16x8* a, const bf16x8* bf, f32x4* out) {
#pragma unroll
  for (int t = 0; t < T; ++t) {
    f32x4 acc = (f32x4){0, 0, 0, 0};
#pragma unroll
    for (int ks = 0; ks < KS; ++ks)
      acc = __builtin_amdgcn_mfma_f32_16x16x32_bf16(a[t * KS + ks], bf[ks], acc, 0, 0, 0);
    out[t] = acc;
  }
}
template<int T, int KS>
__device__ __forceinline__ void mfmacc(const bf16x8* a, const bf16x8* bf, f32x4* out) {
#pragma unroll
  for (int t = 0; t < T; ++t)
#pragma unroll
    for (int ks = 0; ks < KS; ++ks)
      out[t] = __builtin_amdgcn_mfma_f32_16x16x32_bf16(a[t * KS + ks], bf[ks], out[t], 0, 0, 0);
}

__device__ __forceinline__ void put2(ushort* b, int cg, int col, const f32x4& d) {
  uint2 p; p.x = pk2(d[0], d[1]); p.y = pk2(d[2], d[3]);
  *(uint2*)(b + cg + col) = p;
}
__device__ __forceinline__ bf16x8 getf(const ushort* b, int cg, int col, int g) {
  return *(const bf16x8*)(b + cg + col + 8 * g);
}
__device__ __forceinline__ bf16x8 ldf8(const float* __restrict__ p) {
  float4 a = *(const float4*)p, b4 = *(const float4*)(p + 4);
  union { unsigned u[4]; bf16x8 v; } r;
  r.u[0] = pk2(a.x, a.y); r.u[1] = pk2(a.z, a.w);
  r.u[2] = pk2(b4.x, b4.y); r.u[3] = pk2(b4.z, b4.w);
  return r.v;
}
__device__ __forceinline__ f32x4 silu4(const f32x4& d) {
  f32x4 o;
#pragma unroll
  for (int r = 0; r < 4; ++r) { float z = d[r] * 0.125f; o[r] = BETA * z / (1.f + __expf(-z)); }
  return o;
}
__device__ __forceinline__ void vecwin(const float* __restrict__ p,
                                       float y0, float y1, float y2,
                                       bf16x8& dotf, bf16x8* xvf) {
  float v[24];
#pragma unroll
  for (int q = 0; q < 6; ++q) *(float4*)&v[4 * q] = *(const float4*)(p + 4 * q);
  float dj[8];
#pragma unroll
  for (int j = 0; j < 8; ++j)
    dj[j] = (v[3 * j] * y0 + v[3 * j + 1] * y1 + v[3 * j + 2] * y2) * RSQ3;
  union { unsigned u[4]; bf16x8 w; } t;
#pragma unroll
  for (int q = 0; q < 4; ++q) t.u[q] = pk2(dj[2 * q], dj[2 * q + 1]);
  dotf = t.w;
#pragma unroll
  for (int i = 0; i < 3; ++i) {
#pragma unroll
    for (int q = 0; q < 4; ++q) t.u[q] = pk2(v[6 * q + i], v[6 * q + 3 + i]);
    xvf[i] = t.w;
  }
}

// dual-group MLP3: 4 sequential 6-frag chunks (24 VGPR transient)
__device__ __forceinline__ void mlp3_2(const ushort* __restrict__ wb, unsigned lofs,
                                       const bf16x8* h2A, const bf16x8* h2B,
                                       uint2* WpA, uint2* WpB) {
#pragma unroll
  for (int q = 0; q < 4; ++q) {
    bf16x8 a[6];
    lda<6>(wb + q * 6 * 512, lofs, a);
    f32x4 dw[3];
    mfm<3, 2>(a, h2A, dw);
#pragma unroll
    for (int t = 0; t < 3; ++t) {
      WpA[q*3+t].x = pk2(dw[t][0]*0.125f, dw[t][1]*0.125f);
      WpA[q*3+t].y = pk2(dw[t][2]*0.125f, dw[t][3]*0.125f);
    }
    mfm<3, 2>(a, h2B, dw);
#pragma unroll
    for (int t = 0; t < 3; ++t) {
      WpB[q*3+t].x = pk2(dw[t][0]*0.125f, dw[t][1]*0.125f);
      WpB[q*3+t].y = pk2(dw[t][2]*0.125f, dw[t][3]*0.125f);
    }
  }
}

// dual-group TP + folded SL. Shares all weight loads between groups A/B.
template<bool ED, bool ACC>
__device__ __forceinline__ void tp_sl2(
    const ushort* __restrict__ WF, ushort* bA, int cgA, int cgB, int g, unsigned lofs,
    const bf16x8* xsfA, const bf16x8* xsfB,
    const bf16x8* dotA, const bf16x8* dotB,
    const bf16x8* xvA,  const bf16x8* xvB,
    const uint2* WpA, const uint2* WpB,
    float ysA, float ysB,
    float yvA0, float yvA1, float yvA2,
    float yvB0, float yvB1, float yvB2,
    f32x4* osA, f32x4* osB, f32x4 (*ovA)[2], f32x4 (*ovB)[2]) {
  constexpr int KA = ED ? 2 : 4;
  constexpr int KB = ED ? 1 : 2;
  const float SA = ED ? RS64 : RS128;
  const float SB = ED ? RS32 : RS64;

  // s_a -> MSP[0..63], 2 tiles per chunk
#pragma unroll
  for (int half = 0; half < 2; ++half) {
    bf16x8 a[2 * KA];
    lda<2 * KA>(WF + (ED ? O_ess : O_nss) + half * 2 * KA * 512, lofs, a);
    f32x4 dA[2], dB[2];
    mfm<2, KA>(a, xsfA, dA); mfm<2, KA>(a, xsfB, dB);
#pragma unroll
    for (int t = 0; t < 2; ++t) {
      int tt = half * 2 + t;
      f32x4 m;
      m[0] = dA[t][0]*ysA*SA*plo(WpA[tt].x); m[1] = dA[t][1]*ysA*SA*phi(WpA[tt].x);
      m[2] = dA[t][2]*ysA*SA*plo(WpA[tt].y); m[3] = dA[t][3]*ysA*SA*phi(WpA[tt].y);
      put2(bA, cgA, MSP + 16 * tt + 4 * g, m);
      m[0] = dB[t][0]*ysB*SA*plo(WpB[tt].x); m[1] = dB[t][1]*ysB*SA*phi(WpB[tt].x);
      m[2] = dB[t][2]*ysB*SA*plo(WpB[tt].y); m[3] = dB[t][3]*ysB*SA*phi(WpB[tt].y);
      put2(bA, cgB, MSP + 16 * tt + 4 * g, m);
    }
  }
  // s_b -> MSP[64..127]
  {
    bf16x8 a[4 * KB];
    lda<4 * KB>(WF + (ED ? O_evv : O_nvv), lofs, a);
    f32x4 dA[4], dB[4];
    mfm<4, KB>(a, dotA, dA); mfm<4, KB>(a, dotB, dB);
#pragma unroll
    for (int t = 0; t < 4; ++t) {
      f32x4 m;
      m[0] = dA[t][0]*SB*plo(WpA[4+t].x); m[1] = dA[t][1]*SB*phi(WpA[4+t].x);
      m[2] = dA[t][2]*SB*plo(WpA[4+t].y); m[3] = dA[t][3]*SB*phi(WpA[4+t].y);
      put2(bA, cgA, MSP + 64 + 16 * t + 4 * g, m);
      m[0] = dB[t][0]*SB*plo(WpB[4+t].x); m[1] = dB[t][1]*SB*phi(WpB[4+t].x);
      m[2] = dB[t][2]*SB*plo(WpB[4+t].y); m[3] = dB[t][3]*SB*phi(WpB[4+t].y);
      put2(bA, cgB, MSP + 64 + 16 * t + 4 * g, m);
    }
  }
  // v_a shared tiles
  f32x4 gaA[2], gaB[2];
  {
    bf16x8 a[2 * KA];
    lda<2 * KA>(WF + (ED ? O_esv : O_nsv), lofs, a);
    mfm<2, KA>(a, xsfA, gaA); mfm<2, KA>(a, xsfB, gaB);
  }
  bf16x8 avs[2 * KB];
  lda<2 * KB>(WF + (ED ? O_evs : O_nvs), lofs, avs);
  bf16x8 acv[4];
  lda<4>(WF + (ED ? O_cev : O_cnv), lofs, acv);
#pragma unroll
  for (int i = 0; i < 3; ++i) {
    f32x4 dbA[2], dbB[2];
    mfm<2, KB>(avs, xvA + i * KB, dbA);
    mfm<2, KB>(avs, xvB + i * KB, dbB);
    float yviA = (i == 0) ? yvA0 : ((i == 1) ? yvA1 : yvA2);
    float yviB = (i == 0) ? yvB0 : ((i == 1) ? yvB1 : yvB2);
#pragma unroll
    for (int t = 0; t < 2; ++t) {
      f32x4 m;
      m[0] = gaA[t][0]*SA*yviA*plo(WpA[8+t].x); m[1] = gaA[t][1]*SA*yviA*phi(WpA[8+t].x);
      m[2] = gaA[t][2]*SA*yviA*plo(WpA[8+t].y); m[3] = gaA[t][3]*SA*yviA*phi(WpA[8+t].y);
      put2(bA, cgA, MV + 16 * t + 4 * g, m);
      m[0] = gaB[t][0]*SA*yviB*plo(WpB[8+t].x); m[1] = gaB[t][1]*SA*yviB*phi(WpB[8+t].x);
      m[2] = gaB[t][2]*SA*yviB*plo(WpB[8+t].y); m[3] = gaB[t][3]*SA*yviB*phi(WpB[8+t].y);
      put2(bA, cgB, MV + 16 * t + 4 * g, m);
    }
#pragma unroll
    for (int t = 0; t < 2; ++t) {
      f32x4 m;
      m[0] = dbA[t][0]*ysA*SB*plo(WpA[10+t].x); m[1] = dbA[t][1]*ysA*SB*phi(WpA[10+t].x);
      m[2] = dbA[t][2]*ysA*SB*plo(WpA[10+t].y); m[3] = dbA[t][3]*ysA*SB*phi(WpA[10+t].y);
      put2(bA, cgA, MV + 32 + 16 * t + 4 * g, m);
      m[0] = dbB[t][0]*ysB*SB*plo(WpB[10+t].x); m[1] = dbB[t][1]*ysB*SB*phi(WpB[10+t].x);
      m[2] = dbB[t][2]*ysB*SB*plo(WpB[10+t].y); m[3] = dbB[t][3]*ysB*SB*phi(WpB[10+t].y);
      put2(bA, cgB, MV + 32 + 16 * t + 4 * g, m);
    }
    FENCE();
    bf16x8 mvfA[2] = { getf(bA, cgA, MV, g), getf(bA, cgA, MV + 32, g) };
    bf16x8 mvfB[2] = { getf(bA, cgB, MV, g), getf(bA, cgB, MV + 32, g) };
    if (ACC) { mfmacc<2, 2>(acv, mvfA, ovA[i]); mfmacc<2, 2>(acv, mvfB, ovB[i]); }
    else     { mfm<2, 2>(acv, mvfA, ovA[i]);    mfm<2, 2>(acv, mvfB, ovB[i]); }
    FENCE();
  }
  // folded SL-s, 2 chunks of 8 frags (tiles 2h..2h+1 x 4 ks)
  bf16x8 mpfA[4], mpfB[4];
#pragma unroll
  for (int ks = 0; ks < 4; ++ks) {
    mpfA[ks] = getf(bA, cgA, MSP + 32 * ks, g);
    mpfB[ks] = getf(bA, cgB, MSP + 32 * ks, g);
  }
#pragma unroll
  for (int h = 0; h < 2; ++h) {
    bf16x8 a[8];
    lda<8>(WF + (ED ? O_ces : O_cns) + h * 8 * 512, lofs, a);
    if (ACC) { mfmacc<2, 4>(a, mpfA, osA + 2 * h); mfmacc<2, 4>(a, mpfB, osB + 2 * h); }
    else     { mfm<2, 4>(a, mpfA, osA + 2 * h);    mfm<2, 4>(a, mpfB, osB + 2 * h); }
  }
}

__global__ __launch_bounds__(64, 2) void mp_kernel(Ptrs P) {
  const int lane = threadIdx.x & 63;
  const int c    = lane & 15, g  = lane >> 4;
  const unsigned lofs = lane * 8;
  const int cgA  = c * ST;
  const int cgB  = (c + 16) * ST;
  const int eA   = blockIdx.x * 32 + c;
  const int eB   = eA + 16;
  const ushort* __restrict__ WF = P.wf;

  __shared__ ushort sb[32][ST];   // 16,640 B
  ushort* bA = &sb[0][0];

  const float* __restrict__ rsA = P.src + (size_t)eA * 160;
  const float* __restrict__ rdA = P.dst + (size_t)eA * 160;
  const float* __restrict__ reA = P.ef  + (size_t)eA * 160;
  const float* __restrict__ rqA = P.scal + (size_t)eA * 64;
  const float* __restrict__ rsB = P.src + (size_t)eB * 160;
  const float* __restrict__ rdB = P.dst + (size_t)eB * 160;
  const float* __restrict__ reB = P.ef  + (size_t)eB * 160;
  const float* __restrict__ rqB = P.scal + (size_t)eB * 64;

  float4 evA = *(const float4*)(P.env + (size_t)eA * 4);
  float4 evB = *(const float4*)(P.env + (size_t)eB * 4);
  const float ysA = evA.x, yvA0 = evA.y, yvA1 = evA.z, yvA2 = evA.w;
  const float ysB = evB.x, yvB0 = evB.y, yvB1 = evB.z, yvB2 = evB.w;

  // ---- MLP1 (shared weights, both groups) ----
  {
    bf16x8 a1n[8], a1e[8];
    lda<8>(WF + O_nm1, lofs, a1n);
    lda<8>(WF + O_em1, lofs, a1e);
    bf16x8 scA[2], scB[2];
    scA[0] = ldf8(rqA + 8 * g); scA[1] = ldf8(rqA + 32 + 8 * g);
    scB[0] = ldf8(rqB + 8 * g); scB[1] = ldf8(rqB + 32 + 8 * g);
    f32x4 d[4];
    mfm<4, 2>(a1n, scA, d);
#pragma unroll
    for (int t = 0; t < 4; ++t) put2(bA, cgA, H0n + 16 * t + 4 * g, silu4(d[t]));
    mfm<4, 2>(a1n, scB, d);
#pragma unroll
    for (int t = 0; t < 4; ++t) put2(bA, cgB, H0n + 16 * t + 4 * g, silu4(d[t]));
    mfm<4, 2>(a1e, scA, d);
#pragma unroll
    for (int t = 0; t < 4; ++t) put2(bA, cgA, H0e + 16 * t + 4 * g, silu4(d[t]));
    mfm<4, 2>(a1e, scB, d);
#pragma unroll
    for (int t = 0; t < 4; ++t) put2(bA, cgB, H0e + 16 * t + 4 * g, silu4(d[t]));
  }
  FENCE();

  // ---- node TP input streams (both groups) ----
  bf16x8 xsf_nA[4], xsf_nB[4];
  xsf_nA[0] = ldf8(rsA + 8 * g);  xsf_nA[1] = ldf8(rsA + 32 + 8 * g);
  xsf_nA[2] = ldf8(rdA + 8 * g);  xsf_nA[3] = ldf8(rdA + 32 + 8 * g);
  xsf_nB[0] = ldf8(rsB + 8 * g);  xsf_nB[1] = ldf8(rsB + 32 + 8 * g);
  xsf_nB[2] = ldf8(rdB + 8 * g);  xsf_nB[3] = ldf8(rdB + 32 + 8 * g);
  bf16x8 dot_nA[2], xv_nA[6], dot_nB[2], xv_nB[6];
  {
    bf16x8 tmp[3];
    vecwin(rsA + 64 + 24 * g, yvA0, yvA1, yvA2, dot_nA[0], tmp);
    xv_nA[0] = tmp[0]; xv_nA[2] = tmp[1]; xv_nA[4] = tmp[2];
    vecwin(rdA + 64 + 24 * g, yvA0, yvA1, yvA2, dot_nA[1], tmp);
    xv_nA[1] = tmp[0]; xv_nA[3] = tmp[1]; xv_nA[5] = tmp[2];
    vecwin(rsB + 64 + 24 * g, yvB0, yvB1, yvB2, dot_nB[0], tmp);
    xv_nB[0] = tmp[0]; xv_nB[2] = tmp[1]; xv_nB[4] = tmp[2];
    vecwin(rdB + 64 + 24 * g, yvB0, yvB1, yvB2, dot_nB[1], tmp);
    xv_nB[1] = tmp[0]; xv_nB[3] = tmp[1]; xv_nB[5] = tmp[2];
  }

  // ---- MLP2 (shared weights) ----
  {
    bf16x8 a2[8];
    lda<8>(WF + O_nm2, lofs, a2);
    bf16x8 hA[2] = { getf(bA, cgA, H0n, g), getf(bA, cgA, H0n + 32, g) };
    bf16x8 hB[2] = { getf(bA, cgB, H0n, g), getf(bA, cgB, H0n + 32, g) };
    f32x4 d[4];
    mfm<4, 2>(a2, hA, d);
#pragma unroll
    for (int t = 0; t < 4; ++t) put2(bA, cgA, H1n + 16 * t + 4 * g, silu4(d[t]));
    mfm<4, 2>(a2, hB, d);
#pragma unroll
    for (int t = 0; t < 4; ++t) put2(bA, cgB, H1n + 16 * t + 4 * g, silu4(d[t]));
    lda<8>(WF + O_em2, lofs, a2);
    hA[0] = getf(bA, cgA, H0e, g); hA[1] = getf(bA, cgA, H0e + 32, g);
    hB[0] = getf(bA, cgB, H0e, g); hB[1] = getf(bA, cgB, H0e + 32, g);
    mfm<4, 2>(a2, hA, d);
#pragma unroll
    for (int t = 0; t < 4; ++t) put2(bA, cgA, H1e + 16 * t + 4 * g, silu4(d[t]));
    mfm<4, 2>(a2, hB, d);
#pragma unroll
    for (int t = 0; t < 4; ++t) put2(bA, cgB, H1e + 16 * t + 4 * g, silu4(d[t]));
  }
  FENCE();

  // ---- node MLP3 (dual) ----
  uint2 WpnA[12], WpnB[12];
  {
    bf16x8 h2A[2] = { getf(bA, cgA, H1n, g), getf(bA, cgA, H1n + 32, g) };
    bf16x8 h2B[2] = { getf(bA, cgB, H1n, g), getf(bA, cgB, H1n + 32, g) };
    mlp3_2(WF + O_nm3, lofs, h2A, h2B, WpnA, WpnB);
  }
  FENCE();

  // ---- node TP + folded SL (overwrite) ----
  f32x4 osA[4], osB[4]; f32x4 ovA[3][2], ovB[3][2];
  tp_sl2<false, false>(WF, bA, cgA, cgB, g, lofs,
                       xsf_nA, xsf_nB, dot_nA, dot_nB, xv_nA, xv_nB,
                       WpnA, WpnB, ysA, ysB, yvA0, yvA1, yvA2, yvB0, yvB1, yvB2,
                       osA, osB, ovA, ovB);

  // ---- edge MLP3 (dual) ----
  uint2 WpeA[12], WpeB[12];
  {
    bf16x8 h2A[2] = { getf(bA, cgA, H1e, g), getf(bA, cgA, H1e + 32, g) };
    bf16x8 h2B[2] = { getf(bA, cgB, H1e, g), getf(bA, cgB, H1e + 32, g) };
    mlp3_2(WF + O_em3, lofs, h2A, h2B, WpeA, WpeB);
  }
  FENCE();

  // ---- edge TP inputs (both groups) ----
  bf16x8 xsf_eA[2], xsf_eB[2], dot_eA[1], dot_eB[1], xv_eA[3], xv_eB[3];
  xsf_eA[0] = ldf8(reA + 8 * g); xsf_eA[1] = ldf8(reA + 32 + 8 * g);
  xsf_eB[0] = ldf8(reB + 8 * g); xsf_eB[1] = ldf8(reB + 32 + 8 * g);
  vecwin(reA + 64 + 24 * g, yvA0, yvA1, yvA2, dot_eA[0], xv_eA);
  vecwin(reB + 64 + 24 * g, yvB0, yvB1, yvB2, dot_eB[0], xv_eB);

  // ---- edge TP + folded SL (accumulate) ----
  tp_sl2<true, true>(WF, bA, cgA, cgB, g, lofs,
                     xsf_eA, xsf_eB, dot_eA, dot_eB, xv_eA, xv_eB,
                     WpeA, WpeB, ysA, ysB, yvA0, yvA1, yvA2, yvB0, yvB1, yvB2,
                     osA, osB, ovA, ovB);

  // ---- stores ----
  {
    float* __restrict__ po = P.out + (size_t)eA * 160;
#pragma unroll
    for (int t = 0; t < 4; ++t) {
      float4 o = { osA[t][0], osA[t][1], osA[t][2], osA[t][3] };
      *(float4*)(po + 16 * t + 4 * g) = o;
    }
#pragma unroll
    for (int t = 0; t < 2; ++t) {
      float vv[12];
#pragma unroll
      for (int r = 0; r < 4; ++r)
#pragma unroll
        for (int i = 0; i < 3; ++i) vv[3 * r + i] = ovA[i][t][r];
      *(float4*)(po + 64 + 48 * t + 12 * g)     = *(float4*)&vv[0];
      *(float4*)(po + 64 + 48 * t + 12 * g + 4) = *(float4*)&vv[4];
      *(float4*)(po + 64 + 48 * t + 12 * g + 8) = *(float4*)&vv[8];
    }
  }
  {
    float* __restrict__ po = P.out + (size_t)eB * 160;
#pragma unroll
    for (int t = 0; t < 4; ++t) {
      float4 o = { osB[t][0], osB[t][1], osB[t][2], osB[t][3] };
      *(float4*)(po + 16 * t + 4 * g) = o;
    }
#pragma unroll
    for (int t = 0; t < 2; ++t) {
      float vv[12];
#pragma unroll
      for (int r = 0; r < 4; ++r)
#pragma unroll
        for (int i = 0; i < 3; ++i) vv[3 * r + i] = ovB[i][t][r];
      *(float4*)(po + 64 + 48 * t + 12 * g)     = *(float4*)&vv[0];
      *(float4*)(po + 64 + 48 * t + 12 * g + 4) = *(float4*)&vv[4];
      *(float4*)(po + 64 + 48 * t + 12 * g + 8) = *(float4*)&vv[8];
    }
  }
}

extern "C" void kernel_launch(void* const* d_in, const int* in_sizes, int n_in,
                              void* d_out, int out_size, void* d_ws, size_t ws_size,
                              hipStream_t stream) {
  PrepArgs A;
  const int src_idx[14] = {21,22,23, 24,25,26, 5,7,6,8, 9,11,10,12};
  const int Ks[14] = {64,64,64, 64,64,64, 128,128,64,64, 64,64,32,32};
  const int Ns[14] = {64,64,192, 64,64,192, 64,32,64,32, 64,32,64,32};
  const int Os[14] = {O_nm1,O_nm2,O_nm3, O_em1,O_em2,O_em3,
                      O_nss,O_nsv,O_nvv,O_nvs, O_ess,O_esv,O_evv,O_evs};
  for (int i = 0; i < 14; ++i) {
    A.src[i] = (const float*)d_in[src_idx[i]];
    A.K[i] = Ks[i]; A.N[i] = Ns[i]; A.ofs[i] = Os[i];
  }
  A.dst = (ushort*)d_ws;
  prep_kernel<<<dim3(14), dim3(256), 0, stream>>>(A);

  Prep2Args Z;
  Z.A[0] = (const float*)d_in[13]; Z.B[0] = (const float*)d_in[17];
  Z.K[0] = 128; Z.N[0] = 64; Z.inner[0] = 64; Z.ofs[0] = O_cns; Z.scale[0] = RS128 * RS64;
  Z.A[1] = (const float*)d_in[14]; Z.B[1] = (const float*)d_in[18];
  Z.K[1] = 64;  Z.N[1] = 32; Z.inner[1] = 32; Z.ofs[1] = O_cnv; Z.scale[1] = RS64 * RS32;
  Z.A[2] = (const float*)d_in[15]; Z.B[2] = (const float*)d_in[19];
  Z.K[2] = 128; Z.N[2] = 64; Z.inner[2] = 64; Z.ofs[2] = O_ces; Z.scale[2] = RS128 * RS64;
  Z.A[3] = (const float*)d_in[16]; Z.B[3] = (const float*)d_in[20];
  Z.K[3] = 64;  Z.N[3] = 32; Z.inner[3] = 32; Z.ofs[3] = O_cev; Z.scale[3] = RS64 * RS32;
  Z.dst = (ushort*)d_ws;
  prep2_kernel<<<dim3(4, 4), dim3(256), 0, stream>>>(Z);

  Ptrs P;
  P.src  = (const float*)d_in[0];
  P.dst  = (const float*)d_in[1];
  P.ef   = (const float*)d_in[2];
  P.env  = (const float*)d_in[3];
  P.scal = (const float*)d_in[4];
  P.wf   = (const ushort*)d_ws;
  P.out  = (float*)d_out;

  const int E = in_sizes[0] / 160;  // 131072
  mp_kernel<<<dim3(E / 32), dim3(64), 0, stream>>>(P);
}